// Round 9
// baseline (1180.845 us; speedup 1.0000x reference)
//
#include <hip/hip_runtime.h>
#include <hip/hip_bf16.h>
#include <stdint.h>

#define N_NODES 100000
#define N_EDGES 1600000
#define FEAT 128
#define EMB 128
#define N_ROOTS 4096

#define BUCKET_BITS 9
#define BUCKET_NODES 512
#define NBUCK ((N_NODES + BUCKET_NODES - 1) / BUCKET_NODES)  // 196
#define BUCK_CAP 12288
#define BIN_CHUNK 4096
#define NB_BIN ((N_EDGES + BIN_CHUNK - 1) / BIN_CHUNK)       // 391
#define SRCS_CAP (N_EDGES + N_NODES * 8 + 256)

#define SLAB16R ((size_t)(N_NODES + 8) * 16)   // ushorts per 16-col slab (incl. zero row)

typedef __attribute__((ext_vector_type(4))) float f32x4;
typedef __attribute__((ext_vector_type(8))) short bf16x8;

__device__ __forceinline__ ushort f2b(float f) {
  uint32_t u = __float_as_uint(f);
  uint32_t r = (u + 0x7FFFu + ((u >> 16) & 1u)) >> 16;  // RNE
  return (ushort)r;
}

// f32 row-major [n][128] -> bf16 sliced [8 slabs][n][16]
__global__ void k_cvt_sliced(const float* __restrict__ in, ushort* __restrict__ out, int n) {
  int g = blockIdx.x * blockDim.x + threadIdx.x;
  int stride = gridDim.x * blockDim.x;
  int total = n * 16;
  for (; g < total; g += stride) {
    int node = g >> 4, cg = g & 15;
    const float4* p = (const float4*)(in + (size_t)node * 128 + cg * 8);
    float4 v0 = p[0], v1 = p[1];
    uint32_t w0 = (uint32_t)f2b(v0.x) | ((uint32_t)f2b(v0.y) << 16);
    uint32_t w1 = (uint32_t)f2b(v0.z) | ((uint32_t)f2b(v0.w) << 16);
    uint32_t w2 = (uint32_t)f2b(v1.x) | ((uint32_t)f2b(v1.y) << 16);
    uint32_t w3 = (uint32_t)f2b(v1.z) | ((uint32_t)f2b(v1.w) << 16);
    int slab = cg >> 1, off8 = (cg & 1) * 8;
    *(uint4*)(out + (size_t)slab * SLAB16R + (size_t)node * 16 + off8) = make_uint4(w0, w1, w2, w3);
  }
}

// ---- bucketed CSR build, padded to 8-edge multiples per node ----
__global__ __launch_bounds__(256) void k_bin(const int* __restrict__ srcA, const int* __restrict__ dstA,
                                             int* __restrict__ bucket_cnt, int* __restrict__ binned) {
  __shared__ int hist[NBUCK];
  __shared__ int lscan[NBUCK];
  __shared__ int rsv[NBUCK];
  __shared__ int lpos[NBUCK];
  __shared__ int ws[4];
  __shared__ int2 ent[BIN_CHUNK];
  int t = threadIdx.x;
  int e0 = blockIdx.x * BIN_CHUNK;
  int cnt = min(BIN_CHUNK, N_EDGES - e0);
  for (int i = t; i < NBUCK; i += 256) hist[i] = 0;
  __syncthreads();
  for (int j = t; j < cnt; j += 256) atomicAdd(&hist[dstA[e0 + j] >> BUCKET_BITS], 1);
  __syncthreads();
  {
    int lane = t & 63, wv = t >> 6;
    int v = (t < NBUCK) ? hist[t] : 0;
    int inc = v;
    for (int d = 1; d < 64; d <<= 1) { int x = __shfl_up(inc, d); if (lane >= d) inc += x; }
    if (lane == 63) ws[wv] = inc;
    __syncthreads();
    int wbase = 0;
    for (int k = 0; k < wv; ++k) wbase += ws[k];
    if (t < NBUCK) {
      int excl = wbase + inc - v;
      lscan[t] = excl;
      lpos[t] = excl;
      rsv[t] = (v > 0) ? atomicAdd(&bucket_cnt[t], v) : 0;
    }
  }
  __syncthreads();
  for (int j = t; j < cnt; j += 256) {
    int s = srcA[e0 + j], d = dstA[e0 + j];
    int p = atomicAdd(&lpos[d >> BUCKET_BITS], 1);
    ent[p] = make_int2(s, d);
  }
  __syncthreads();
  for (int j = t; j < cnt; j += 256) {
    int2 E = ent[j];
    int b = E.y >> BUCKET_BITS;
    int pos = rsv[b] + (j - lscan[b]);
    if (pos < BUCK_CAP)
      binned[b * BUCK_CAP + pos] = (E.x << BUCKET_BITS) | (E.y & (BUCKET_NODES - 1));
  }
}

__global__ __launch_bounds__(512) void k_deg(const int* __restrict__ binned,
                                             const int* __restrict__ bucket_cnt,
                                             int* __restrict__ degg, int* __restrict__ pad_cnt) {
  __shared__ int deg[BUCKET_NODES];
  __shared__ int ws[8];
  int b = blockIdx.x, t = threadIdx.x;
  int cnt = min(bucket_cnt[b], BUCK_CAP);
  deg[t] = 0;
  __syncthreads();
  for (int j = t; j < cnt; j += 512) atomicAdd(&deg[binned[b * BUCK_CAP + j] & (BUCKET_NODES - 1)], 1);
  __syncthreads();
  int n0 = b * BUCKET_NODES;
  int nn = min(BUCKET_NODES, N_NODES - n0);
  int d = (t < nn) ? deg[t] : 0;
  if (t < nn) degg[n0 + t] = d;
  int dp = (d + 7) & ~7;
  int lane = t & 63, wv = t >> 6;
  for (int q = 1; q < 64; q <<= 1) dp += __shfl_xor(dp, q);
  if (lane == 0) ws[wv] = dp;
  __syncthreads();
  if (t == 0) {
    int tot = 0;
    for (int k = 0; k < 8; ++k) tot += ws[k];
    pad_cnt[b] = tot;
  }
}

__global__ __launch_bounds__(256) void k_bucket_scan(const int* __restrict__ pad_cnt,
                                                     int* __restrict__ bucket_base,
                                                     int* __restrict__ off_last) {
  __shared__ int ws[4];
  int t = threadIdx.x;
  int lane = t & 63, wv = t >> 6;
  int v = (t < NBUCK) ? pad_cnt[t] : 0;
  int inc = v;
  for (int d = 1; d < 64; d <<= 1) { int x = __shfl_up(inc, d); if (lane >= d) inc += x; }
  if (lane == 63) ws[wv] = inc;
  __syncthreads();
  int wbase = 0;
  for (int k = 0; k < wv; ++k) wbase += ws[k];
  if (t < NBUCK) bucket_base[t] = wbase + inc - v;
  if (t == NBUCK - 1) *off_last = wbase + inc;
}

__global__ __launch_bounds__(512) void k_csr(const int* __restrict__ binned,
                                             const int* __restrict__ bucket_cnt,
                                             const int* __restrict__ bucket_base,
                                             const int* __restrict__ degg,
                                             int* __restrict__ off, int* __restrict__ srcs) {
  __shared__ int sAb[BUCKET_NODES];
  __shared__ int sBb[BUCKET_NODES];
  __shared__ int pos[BUCKET_NODES];
  __shared__ int dreal[BUCKET_NODES];
  __shared__ int epk[BUCK_CAP];
  int b = blockIdx.x;
  int t = threadIdx.x;
  int cnt = min(bucket_cnt[b], BUCK_CAP);
  int gbase = bucket_base[b];
  int n0 = b * BUCKET_NODES;
  int nn = min(BUCKET_NODES, N_NODES - n0);
  int d = (t < nn) ? degg[n0 + t] : 0;
  dreal[t] = d;
  int dp = (d + 7) & ~7;
  int* sA = sAb; int* sB = sBb;
  sA[t] = dp;
  __syncthreads();
  for (int q = 1; q < 512; q <<= 1) {
    int x = sA[t];
    if (t >= q) x += sA[t - q];
    sB[t] = x;
    __syncthreads();
    int* tp = sA; sA = sB; sB = tp;
  }
  int ex = sA[t] - dp;
  pos[t] = ex;
  if (t < nn) off[n0 + t] = gbase + ex;
  __syncthreads();
  for (int j = t; j < cnt; j += 512) epk[j] = binned[b * BUCK_CAP + j];
  __syncthreads();
  for (int j = t; j < cnt; j += 512) {
    int p = epk[j];
    int q = atomicAdd(&pos[p & (BUCKET_NODES - 1)], 1);
    srcs[gbase + q] = p >> BUCKET_BITS;
  }
  __syncthreads();
  int start = sA[t] - dp;
  int fill0 = start + dreal[t];
  int fill1 = start + ((dreal[t] + 7) & ~7);
  for (int q = fill0; q < fill1; ++q) srcs[gbase + q] = N_NODES;  // zero-row dummy
}

// ---- degree counting sort (nodes batched by degree for the sliced aggr) ----
__global__ void k_dhist(const int* __restrict__ degg, int* __restrict__ dbin, int* __restrict__ rbin) {
  __shared__ int h[64], rh[64];
  int t = threadIdx.x;
  if (t < 64) { h[t] = 0; rh[t] = 0; }
  __syncthreads();
  int i = blockIdx.x * blockDim.x + t;
  int stride = gridDim.x * blockDim.x;
  for (; i < N_NODES; i += stride) {
    int b = min(degg[i] >> 3, 63);
    atomicAdd(&h[b], 1);
    if (i < N_ROOTS) atomicAdd(&rh[b], 1);
  }
  __syncthreads();
  if (t < 64) {
    if (h[t]) atomicAdd(&dbin[t], h[t]);
    if (rh[t]) atomicAdd(&rbin[t], rh[t]);
  }
}

__global__ void k_dscan(const int* __restrict__ dbin, const int* __restrict__ rbin,
                        int* __restrict__ dcur, int* __restrict__ rcur) {
  int t = threadIdx.x;  // 64
  int v = dbin[t], r = rbin[t];
  int iv = v, ir = r;
  for (int d = 1; d < 64; d <<= 1) {
    int x = __shfl_up(iv, d); if (t >= d) iv += x;
    int y = __shfl_up(ir, d); if (t >= d) ir += y;
  }
  dcur[t] = iv - v;
  rcur[t] = ir - r;
}

__global__ void k_dscat(const int* __restrict__ degg, int* __restrict__ dcur, int* __restrict__ rcur,
                        int* __restrict__ order, int* __restrict__ rorder) {
  int i = blockIdx.x * blockDim.x + threadIdx.x;
  int stride = gridDim.x * blockDim.x;
  for (; i < N_NODES; i += stride) {
    int b = min(degg[i] >> 3, 63);
    int p = atomicAdd(&dcur[b], 1);
    order[p] = i;
    if (i < N_ROOTS) {
      int p2 = atomicAdd(&rcur[b], 1);
      rorder[p2] = i;
    }
  }
}

// sliced GEMM, 512 thr / 256-row tile: out[slab][row][16](bf16) = A @ W
__global__ __launch_bounds__(512) void k_gemm(
    const ushort* __restrict__ A0, const ushort* __restrict__ A1,
    const float* __restrict__ W, ushort* __restrict__ out, int n, int K, int relu0)
{
  extern __shared__ char smem[];  // W^T swizzled: (k,c) -> byte c*2K + ((2k)^((c&7)<<4))
  const int KC = K * 128;
  for (int idx = threadIdx.x; idx < KC; idx += 512) {
    int k = idx >> 7, c = idx & 127;
    ushort b = f2b(W[idx]);
    *(ushort*)(smem + c * (K * 2) + ((k * 2) ^ ((c & 7) << 4))) = b;
  }
  __syncthreads();

  int lane = threadIdx.x & 63;
  int wv = threadIdx.x >> 6;          // 0..7
  int rowBase = blockIdx.x * 256 + wv * 32;
  int rl = lane & 15;
  int kh = lane >> 4;
  int r0 = rowBase + rl, r1 = r0 + 16;
  int r0c = min(r0, n - 1), r1c = min(r1, n - 1);

  f32x4 acc[2][8];
#pragma unroll
  for (int i = 0; i < 2; ++i)
#pragma unroll
    for (int j = 0; j < 8; ++j)
      acc[i][j] = (f32x4){0.f, 0.f, 0.f, 0.f};

  int nks = K >> 5;
  for (int ks = 0; ks < nks; ++ks) {
    const ushort* Asrc = (ks < 4) ? A0 : A1;
    int kof = ((ks & 3) << 5) + (kh << 3);   // col 0..127 in that matrix
    const ushort* ap = Asrc + (size_t)(kof >> 4) * SLAB16R + (kof & 15);
    bf16x8 a0 = *(const bf16x8*)(ap + (size_t)r0c * 16);
    bf16x8 a1 = *(const bf16x8*)(ap + (size_t)r1c * 16);
    if (relu0 && ks < 4) {
#pragma unroll
      for (int q = 0; q < 8; ++q) {
        short v0 = a0[q]; a0[q] = (short)(v0 & ~(v0 >> 15));
        short v1 = a1[q]; a1[q] = (short)(v1 & ~(v1 >> 15));
      }
    }
    int kk = (ks << 5) + (kh << 3);
#pragma unroll
    for (int ct = 0; ct < 8; ++ct) {
      int col = (ct << 4) + rl;
      bf16x8 b = *(const bf16x8*)(smem + col * (K * 2) + ((kk * 2) ^ ((col & 7) << 4)));
      acc[0][ct] = __builtin_amdgcn_mfma_f32_16x16x32_bf16(a0, b, acc[0][ct], 0, 0, 0);
      acc[1][ct] = __builtin_amdgcn_mfma_f32_16x16x32_bf16(a1, b, acc[1][ct], 0, 0, 0);
    }
  }
  // C layout: col = ct*16 + rl -> slab ct>>1? No: 16-col slabs -> slab = ct, in-slab col = rl
#pragma unroll
  for (int ri = 0; ri < 2; ++ri)
#pragma unroll
    for (int ct = 0; ct < 8; ++ct) {
#pragma unroll
      for (int j = 0; j < 4; ++j) {
        int row = rowBase + ri * 16 + kh * 4 + j;
        if (row < n) out[(size_t)ct * SLAB16R + (size_t)row * 16 + rl] = f2b(acc[ri][ct][j]);
      }
    }
}

// S=8 sliced segment-sum: slice = blockIdx&7 (XCD-pinned, 3.2MB slab L2-resident).
// Wave = 8 nodes x 8 dword-lanes; each 8-lane group walks its own node's list.
// Nodes batched by degree via `order` so group loop counts match.
__global__ __launch_bounds__(256) void k_aggr(
    const ushort* __restrict__ hlin_s, const int* __restrict__ off, const int* __restrict__ srcs,
    const int* __restrict__ order, const float* __restrict__ bias,
    ushort* __restrict__ hbf_s, float* __restrict__ outf, int count, int first, int last)
{
  int slice = blockIdx.x & 7;
  int grp = blockIdx.x >> 3;
  int wv = threadIdx.x >> 6, lane = threadIdx.x & 63;
  int ns = lane >> 3, cd = lane & 7;
  int gid = grp * 32 + wv * 8 + ns;
  if (gid >= count) return;
  int node = order[gid];
  int s = off[node], e = off[node + 1];
  const uint32_t* slab = (const uint32_t*)hlin_s + (size_t)slice * (SLAB16R / 2);
  float a0 = 0.f, a1 = 0.f;
  for (int j = s; j < e; j += 8) {
    int4 p0 = *(const int4*)(srcs + j);
    int4 p1 = *(const int4*)(srcs + j + 4);
    uint32_t u0 = slab[(size_t)p0.x * 8 + cd];
    uint32_t u1 = slab[(size_t)p0.y * 8 + cd];
    uint32_t u2 = slab[(size_t)p0.z * 8 + cd];
    uint32_t u3 = slab[(size_t)p0.w * 8 + cd];
    uint32_t u4 = slab[(size_t)p1.x * 8 + cd];
    uint32_t u5 = slab[(size_t)p1.y * 8 + cd];
    uint32_t u6 = slab[(size_t)p1.z * 8 + cd];
    uint32_t u7 = slab[(size_t)p1.w * 8 + cd];
    a0 += __uint_as_float(u0 << 16) + __uint_as_float(u1 << 16) +
          __uint_as_float(u2 << 16) + __uint_as_float(u3 << 16) +
          __uint_as_float(u4 << 16) + __uint_as_float(u5 << 16) +
          __uint_as_float(u6 << 16) + __uint_as_float(u7 << 16);
    a1 += __uint_as_float(u0 & 0xFFFF0000u) + __uint_as_float(u1 & 0xFFFF0000u) +
          __uint_as_float(u2 & 0xFFFF0000u) + __uint_as_float(u3 & 0xFFFF0000u) +
          __uint_as_float(u4 & 0xFFFF0000u) + __uint_as_float(u5 & 0xFFFF0000u) +
          __uint_as_float(u6 & 0xFFFF0000u) + __uint_as_float(u7 & 0xFFFF0000u);
  }
  float2 bv = ((const float2*)bias)[slice * 8 + cd];
  uint32_t* hb = (uint32_t*)hbf_s + (size_t)slice * (SLAB16R / 2);
  size_t hi = (size_t)node * 8 + cd;
  float h0, h1;
  if (first) {
    h0 = a0 + bv.x; h1 = a1 + bv.y;
  } else {
    uint32_t up = hb[hi];
    h0 = __uint_as_float(up << 16) + a0 + bv.x;
    h1 = __uint_as_float(up & 0xFFFF0000u) + a1 + bv.y;
  }
  if (last) {
    *(float2*)(outf + (size_t)node * 128 + slice * 16 + cd * 2) = make_float2(h0, h1);
  } else {
    hb[hi] = (uint32_t)f2b(h0) | ((uint32_t)f2b(h1) << 16);
  }
}

extern "C" void kernel_launch(void* const* d_in, const int* in_sizes, int n_in,
                              void* d_out, int out_size, void* d_ws, size_t ws_size,
                              hipStream_t stream) {
  const float* x = (const float*)d_in[0];
  const int* ei  = (const int*)d_in[1];
  const int* src = ei;
  const int* dst = ei + N_EDGES;
  const float* Wp[4] = {(const float*)d_in[4], (const float*)d_in[6],
                        (const float*)d_in[8], (const float*)d_in[10]};
  const float* bp[4] = {(const float*)d_in[5], (const float*)d_in[7],
                        (const float*)d_in[9], (const float*)d_in[11]};

  char* w = (char*)d_ws;
  auto alloc = [&](size_t bytes) {
    char* p = w;
    w += (bytes + 255) & ~(size_t)255;
    return p;
  };
  ushort* xs       = (ushort*)alloc(8 * SLAB16R * 2);
  ushort* hbf_s    = (ushort*)alloc(8 * SLAB16R * 2);
  ushort* hlin_s   = (ushort*)alloc(8 * SLAB16R * 2);
  int*    off      = (int*)   alloc((size_t)(N_NODES + 1) * 4);
  int*    srcs     = (int*)   alloc((size_t)SRCS_CAP * 4);
  int*    binned   = (int*)   alloc((size_t)NBUCK * BUCK_CAP * 4);
  int*    degg     = (int*)   alloc((size_t)N_NODES * 4);
  int*    order    = (int*)   alloc((size_t)N_NODES * 4);
  int*    rorder   = (int*)   alloc((size_t)N_ROOTS * 4);
  int*    bucket_cnt  = (int*)alloc((size_t)NBUCK * 4);
  int*    pad_cnt     = (int*)alloc((size_t)NBUCK * 4);
  int*    bucket_base = (int*)alloc((size_t)(NBUCK + 1) * 4);
  int*    dbin     = (int*)   alloc(64 * 4);
  int*    rbin     = (int*)   alloc(64 * 4);
  int*    dcur     = (int*)   alloc(64 * 4);
  int*    rcur     = (int*)   alloc(64 * 4);
  if ((size_t)(w - (char*)d_ws) > ws_size) return;

  hipMemsetAsync(bucket_cnt, 0, (size_t)NBUCK * 4, stream);
  hipMemsetAsync(dbin, 0, 64 * 4, stream);
  hipMemsetAsync(rbin, 0, 64 * 4, stream);
  // zero row (node N_NODES) per hlin slab for padded dummy edges
  for (int sl = 0; sl < 8; ++sl)
    hipMemsetAsync(hlin_s + (size_t)sl * SLAB16R + (size_t)N_NODES * 16, 0, 32, stream);

  k_cvt_sliced<<<2048, 256, 0, stream>>>(x, xs, N_NODES);
  k_bin<<<NB_BIN, 256, 0, stream>>>(src, dst, bucket_cnt, binned);
  k_deg<<<NBUCK, 512, 0, stream>>>(binned, bucket_cnt, degg, pad_cnt);
  k_bucket_scan<<<1, 256, 0, stream>>>(pad_cnt, bucket_base, off + N_NODES);
  k_csr<<<NBUCK, 512, 0, stream>>>(binned, bucket_cnt, bucket_base, degg, off, srcs);
  k_dhist<<<512, 256, 0, stream>>>(degg, dbin, rbin);
  k_dscan<<<1, 64, 0, stream>>>(dbin, rbin, dcur, rcur);
  k_dscat<<<512, 256, 0, stream>>>(degg, dcur, rcur, order, rorder);

  int gblocks = (N_NODES + 255) / 256;
  int afull = ((N_NODES + 31) / 32) * 8;
  int aroot = ((N_ROOTS + 31) / 32) * 8;
  // layer 0
  k_gemm<<<gblocks, 512, 128 * 128 * 2, stream>>>(xs, xs, Wp[0], hlin_s, N_NODES, 128, 0);
  k_aggr<<<afull, 256, 0, stream>>>(hlin_s, off, srcs, order, bp[0], hbf_s, (float*)d_out,
                                    N_NODES, 1, 0);
  // layers 1..2 full, layer 3 aggregation root-only
  for (int l = 1; l < 4; ++l) {
    k_gemm<<<gblocks, 512, 256 * 128 * 2, stream>>>(hbf_s, xs, Wp[l], hlin_s, N_NODES, 256, 1);
    if (l < 3) {
      k_aggr<<<afull, 256, 0, stream>>>(hlin_s, off, srcs, order, bp[l], hbf_s, (float*)d_out,
                                        N_NODES, 0, 0);
    } else {
      k_aggr<<<aroot, 256, 0, stream>>>(hlin_s, off, srcs, rorder, bp[l], hbf_s, (float*)d_out,
                                        N_ROOTS, 0, 1);
    }
  }
}

// Round 10
// 431.238 us; speedup vs baseline: 2.7383x; 2.7383x over previous
//
#include <hip/hip_runtime.h>
#include <hip/hip_bf16.h>
#include <stdint.h>

#define N_NODES 100000
#define N_EDGES 1600000
#define FEAT 128
#define EMB 128
#define N_ROOTS 4096

#define BUCKET_BITS 9
#define BUCKET_NODES 512
#define NBUCK ((N_NODES + BUCKET_NODES - 1) / BUCKET_NODES)  // 196
#define BUCK_CAP 12288
#define BIN_CHUNK 4096
#define NB_BIN ((N_EDGES + BIN_CHUNK - 1) / BIN_CHUNK)       // 391
#define SRCS_CAP (N_EDGES + N_NODES * 8 + 256)

#define NB_DS 16
#define DS_CHUNK ((N_NODES + NB_DS - 1) / NB_DS)             // 6250

#define SLAB16R ((size_t)(N_NODES + 8) * 16)   // ushorts per 16-col slab (incl. zero row)

typedef __attribute__((ext_vector_type(4))) float f32x4;
typedef __attribute__((ext_vector_type(8))) short bf16x8;

__device__ __forceinline__ ushort f2b(float f) {
  uint32_t u = __float_as_uint(f);
  uint32_t r = (u + 0x7FFFu + ((u >> 16) & 1u)) >> 16;  // RNE
  return (ushort)r;
}

// f32 row-major [n][128] -> bf16 sliced [8 slabs][n][16]
__global__ void k_cvt_sliced(const float* __restrict__ in, ushort* __restrict__ out, int n) {
  int g = blockIdx.x * blockDim.x + threadIdx.x;
  int stride = gridDim.x * blockDim.x;
  int total = n * 16;
  for (; g < total; g += stride) {
    int node = g >> 4, cg = g & 15;
    const float4* p = (const float4*)(in + (size_t)node * 128 + cg * 8);
    float4 v0 = p[0], v1 = p[1];
    uint32_t w0 = (uint32_t)f2b(v0.x) | ((uint32_t)f2b(v0.y) << 16);
    uint32_t w1 = (uint32_t)f2b(v0.z) | ((uint32_t)f2b(v0.w) << 16);
    uint32_t w2 = (uint32_t)f2b(v1.x) | ((uint32_t)f2b(v1.y) << 16);
    uint32_t w3 = (uint32_t)f2b(v1.z) | ((uint32_t)f2b(v1.w) << 16);
    int slab = cg >> 1, off8 = (cg & 1) * 8;
    *(uint4*)(out + (size_t)slab * SLAB16R + (size_t)node * 16 + off8) = make_uint4(w0, w1, w2, w3);
  }
}

// ---- bucketed CSR build, padded to 8-edge multiples per node ----
__global__ __launch_bounds__(256) void k_bin(const int* __restrict__ srcA, const int* __restrict__ dstA,
                                             int* __restrict__ bucket_cnt, int* __restrict__ binned) {
  __shared__ int hist[NBUCK];
  __shared__ int lscan[NBUCK];
  __shared__ int rsv[NBUCK];
  __shared__ int lpos[NBUCK];
  __shared__ int ws[4];
  __shared__ int2 ent[BIN_CHUNK];
  int t = threadIdx.x;
  int e0 = blockIdx.x * BIN_CHUNK;
  int cnt = min(BIN_CHUNK, N_EDGES - e0);
  for (int i = t; i < NBUCK; i += 256) hist[i] = 0;
  __syncthreads();
  for (int j = t; j < cnt; j += 256) atomicAdd(&hist[dstA[e0 + j] >> BUCKET_BITS], 1);
  __syncthreads();
  {
    int lane = t & 63, wv = t >> 6;
    int v = (t < NBUCK) ? hist[t] : 0;
    int inc = v;
    for (int d = 1; d < 64; d <<= 1) { int x = __shfl_up(inc, d); if (lane >= d) inc += x; }
    if (lane == 63) ws[wv] = inc;
    __syncthreads();
    int wbase = 0;
    for (int k = 0; k < wv; ++k) wbase += ws[k];
    if (t < NBUCK) {
      int excl = wbase + inc - v;
      lscan[t] = excl;
      lpos[t] = excl;
      rsv[t] = (v > 0) ? atomicAdd(&bucket_cnt[t], v) : 0;
    }
  }
  __syncthreads();
  for (int j = t; j < cnt; j += 256) {
    int s = srcA[e0 + j], d = dstA[e0 + j];
    int p = atomicAdd(&lpos[d >> BUCKET_BITS], 1);
    ent[p] = make_int2(s, d);
  }
  __syncthreads();
  for (int j = t; j < cnt; j += 256) {
    int2 E = ent[j];
    int b = E.y >> BUCKET_BITS;
    int pos = rsv[b] + (j - lscan[b]);
    if (pos < BUCK_CAP)
      binned[b * BUCK_CAP + pos] = (E.x << BUCKET_BITS) | (E.y & (BUCKET_NODES - 1));
  }
}

__global__ __launch_bounds__(512) void k_deg(const int* __restrict__ binned,
                                             const int* __restrict__ bucket_cnt,
                                             int* __restrict__ degg, int* __restrict__ pad_cnt) {
  __shared__ int deg[BUCKET_NODES];
  __shared__ int ws[8];
  int b = blockIdx.x, t = threadIdx.x;
  int cnt = min(bucket_cnt[b], BUCK_CAP);
  deg[t] = 0;
  __syncthreads();
  for (int j = t; j < cnt; j += 512) atomicAdd(&deg[binned[b * BUCK_CAP + j] & (BUCKET_NODES - 1)], 1);
  __syncthreads();
  int n0 = b * BUCKET_NODES;
  int nn = min(BUCKET_NODES, N_NODES - n0);
  int d = (t < nn) ? deg[t] : 0;
  if (t < nn) degg[n0 + t] = d;
  int dp = (d + 7) & ~7;
  int lane = t & 63, wv = t >> 6;
  for (int q = 1; q < 64; q <<= 1) dp += __shfl_xor(dp, q);
  if (lane == 0) ws[wv] = dp;
  __syncthreads();
  if (t == 0) {
    int tot = 0;
    for (int k = 0; k < 8; ++k) tot += ws[k];
    pad_cnt[b] = tot;
  }
}

__global__ __launch_bounds__(256) void k_bucket_scan(const int* __restrict__ pad_cnt,
                                                     int* __restrict__ bucket_base,
                                                     int* __restrict__ off_last) {
  __shared__ int ws[4];
  int t = threadIdx.x;
  int lane = t & 63, wv = t >> 6;
  int v = (t < NBUCK) ? pad_cnt[t] : 0;
  int inc = v;
  for (int d = 1; d < 64; d <<= 1) { int x = __shfl_up(inc, d); if (lane >= d) inc += x; }
  if (lane == 63) ws[wv] = inc;
  __syncthreads();
  int wbase = 0;
  for (int k = 0; k < wv; ++k) wbase += ws[k];
  if (t < NBUCK) bucket_base[t] = wbase + inc - v;
  if (t == NBUCK - 1) *off_last = wbase + inc;
}

__global__ __launch_bounds__(512) void k_csr(const int* __restrict__ binned,
                                             const int* __restrict__ bucket_cnt,
                                             const int* __restrict__ bucket_base,
                                             const int* __restrict__ degg,
                                             int* __restrict__ off, int* __restrict__ srcs) {
  __shared__ int sAb[BUCKET_NODES];
  __shared__ int sBb[BUCKET_NODES];
  __shared__ int pos[BUCKET_NODES];
  __shared__ int dreal[BUCKET_NODES];
  __shared__ int epk[BUCK_CAP];
  int b = blockIdx.x;
  int t = threadIdx.x;
  int cnt = min(bucket_cnt[b], BUCK_CAP);
  int gbase = bucket_base[b];
  int n0 = b * BUCKET_NODES;
  int nn = min(BUCKET_NODES, N_NODES - n0);
  int d = (t < nn) ? degg[n0 + t] : 0;
  dreal[t] = d;
  int dp = (d + 7) & ~7;
  int* sA = sAb; int* sB = sBb;
  sA[t] = dp;
  __syncthreads();
  for (int q = 1; q < 512; q <<= 1) {
    int x = sA[t];
    if (t >= q) x += sA[t - q];
    sB[t] = x;
    __syncthreads();
    int* tp = sA; sA = sB; sB = tp;
  }
  int ex = sA[t] - dp;
  pos[t] = ex;
  if (t < nn) off[n0 + t] = gbase + ex;
  __syncthreads();
  for (int j = t; j < cnt; j += 512) epk[j] = binned[b * BUCK_CAP + j];
  __syncthreads();
  for (int j = t; j < cnt; j += 512) {
    int p = epk[j];
    int q = atomicAdd(&pos[p & (BUCKET_NODES - 1)], 1);
    srcs[gbase + q] = p >> BUCKET_BITS;
  }
  __syncthreads();
  int start = sA[t] - dp;
  int fill0 = start + dreal[t];
  int fill1 = start + ((dreal[t] + 7) & ~7);
  for (int q = fill0; q < fill1; ++q) srcs[gbase + q] = N_NODES;  // zero-row dummy
}

// ---- degree counting sort: chunked, LDS-staged, padded global counters ----
// bins padded to 128B (stride 32 ints) to avoid same-line atomic ping-pong.
__global__ __launch_bounds__(256) void k_dhist(const int* __restrict__ degg,
                                               int* __restrict__ dbinP, int* __restrict__ rbinP) {
  __shared__ int h[64], rh[64];
  int b = blockIdx.x, t = threadIdx.x;
  if (t < 64) { h[t] = 0; rh[t] = 0; }
  __syncthreads();
  int n0 = b * DS_CHUNK;
  int nn = min(DS_CHUNK, N_NODES - n0);
  for (int i = t; i < nn; i += 256) {
    int bin = min(degg[n0 + i] >> 3, 63);
    atomicAdd(&h[bin], 1);
    if (n0 + i < N_ROOTS) atomicAdd(&rh[bin], 1);
  }
  __syncthreads();
  if (t < 64) {
    if (h[t]) atomicAdd(&dbinP[t * 32], h[t]);
    if (rh[t]) atomicAdd(&rbinP[t * 32], rh[t]);
  }
}

__global__ void k_dscan(const int* __restrict__ dbinP, const int* __restrict__ rbinP,
                        int* __restrict__ dcurP, int* __restrict__ rcurP) {
  int t = threadIdx.x;  // 64
  int v = dbinP[t * 32], r = rbinP[t * 32];
  int iv = v, ir = r;
  for (int d = 1; d < 64; d <<= 1) {
    int x = __shfl_up(iv, d); if (t >= d) iv += x;
    int y = __shfl_up(ir, d); if (t >= d) ir += y;
  }
  dcurP[t * 32] = iv - v;
  rcurP[t * 32] = ir - r;
}

__global__ __launch_bounds__(256) void k_dscat(const int* __restrict__ degg,
                                               int* __restrict__ dcurP, int* __restrict__ rcurP,
                                               int* __restrict__ order, int* __restrict__ rorder) {
  __shared__ int h[64], rh[64], base[64], rbase[64], lp[64], rlp[64];
  __shared__ unsigned char lbin[DS_CHUNK];
  int b = blockIdx.x, t = threadIdx.x;
  if (t < 64) { h[t] = 0; rh[t] = 0; lp[t] = 0; rlp[t] = 0; }
  __syncthreads();
  int n0 = b * DS_CHUNK;
  int nn = min(DS_CHUNK, N_NODES - n0);
  for (int i = t; i < nn; i += 256) {
    int bin = min(degg[n0 + i] >> 3, 63);
    lbin[i] = (unsigned char)bin;
    atomicAdd(&h[bin], 1);
    if (n0 + i < N_ROOTS) atomicAdd(&rh[bin], 1);
  }
  __syncthreads();
  if (t < 64) {
    base[t]  = h[t]  ? atomicAdd(&dcurP[t * 32], h[t])  : 0;   // one atomic per (block,bin)
    rbase[t] = rh[t] ? atomicAdd(&rcurP[t * 32], rh[t]) : 0;
  }
  __syncthreads();
  for (int i = t; i < nn; i += 256) {
    int bin = lbin[i];
    int p = atomicAdd(&lp[bin], 1);
    order[base[bin] + p] = n0 + i;
    if (n0 + i < N_ROOTS) {
      int p2 = atomicAdd(&rlp[bin], 1);
      rorder[rbase[bin] + p2] = n0 + i;
    }
  }
}

// sliced GEMM, 512 thr / 256-row tile: out[slab][row][16](bf16) = A @ W
__global__ __launch_bounds__(512) void k_gemm(
    const ushort* __restrict__ A0, const ushort* __restrict__ A1,
    const float* __restrict__ W, ushort* __restrict__ out, int n, int K, int relu0)
{
  extern __shared__ char smem[];  // W^T swizzled: (k,c) -> byte c*2K + ((2k)^((c&7)<<4))
  const int KC = K * 128;
  for (int idx = threadIdx.x; idx < KC; idx += 512) {
    int k = idx >> 7, c = idx & 127;
    ushort b = f2b(W[idx]);
    *(ushort*)(smem + c * (K * 2) + ((k * 2) ^ ((c & 7) << 4))) = b;
  }
  __syncthreads();

  int lane = threadIdx.x & 63;
  int wv = threadIdx.x >> 6;          // 0..7
  int rowBase = blockIdx.x * 256 + wv * 32;
  int rl = lane & 15;
  int kh = lane >> 4;
  int r0 = rowBase + rl, r1 = r0 + 16;
  int r0c = min(r0, n - 1), r1c = min(r1, n - 1);

  f32x4 acc[2][8];
#pragma unroll
  for (int i = 0; i < 2; ++i)
#pragma unroll
    for (int j = 0; j < 8; ++j)
      acc[i][j] = (f32x4){0.f, 0.f, 0.f, 0.f};

  int nks = K >> 5;
  for (int ks = 0; ks < nks; ++ks) {
    const ushort* Asrc = (ks < 4) ? A0 : A1;
    int kof = ((ks & 3) << 5) + (kh << 3);
    const ushort* ap = Asrc + (size_t)(kof >> 4) * SLAB16R + (kof & 15);
    bf16x8 a0 = *(const bf16x8*)(ap + (size_t)r0c * 16);
    bf16x8 a1 = *(const bf16x8*)(ap + (size_t)r1c * 16);
    if (relu0 && ks < 4) {
#pragma unroll
      for (int q = 0; q < 8; ++q) {
        short v0 = a0[q]; a0[q] = (short)(v0 & ~(v0 >> 15));
        short v1 = a1[q]; a1[q] = (short)(v1 & ~(v1 >> 15));
      }
    }
    int kk = (ks << 5) + (kh << 3);
#pragma unroll
    for (int ct = 0; ct < 8; ++ct) {
      int col = (ct << 4) + rl;
      bf16x8 b = *(const bf16x8*)(smem + col * (K * 2) + ((kk * 2) ^ ((col & 7) << 4)));
      acc[0][ct] = __builtin_amdgcn_mfma_f32_16x16x32_bf16(a0, b, acc[0][ct], 0, 0, 0);
      acc[1][ct] = __builtin_amdgcn_mfma_f32_16x16x32_bf16(a1, b, acc[1][ct], 0, 0, 0);
    }
  }
#pragma unroll
  for (int ri = 0; ri < 2; ++ri)
#pragma unroll
    for (int ct = 0; ct < 8; ++ct) {
#pragma unroll
      for (int j = 0; j < 4; ++j) {
        int row = rowBase + ri * 16 + kh * 4 + j;
        if (row < n) out[(size_t)ct * SLAB16R + (size_t)row * 16 + rl] = f2b(acc[ri][ct][j]);
      }
    }
}

// S=8 sliced segment-sum: slice = blockIdx&7 (XCD-pinned, 3.2MB slab L2-resident).
// Wave = 8 nodes x 8 dword-lanes; nodes degree-batched via `order`.
__global__ __launch_bounds__(256) void k_aggr(
    const ushort* __restrict__ hlin_s, const int* __restrict__ off, const int* __restrict__ srcs,
    const int* __restrict__ order, const float* __restrict__ bias,
    ushort* __restrict__ hbf_s, float* __restrict__ outf, int count, int first, int last)
{
  int slice = blockIdx.x & 7;
  int grp = blockIdx.x >> 3;
  int wv = threadIdx.x >> 6, lane = threadIdx.x & 63;
  int ns = lane >> 3, cd = lane & 7;
  int gid = grp * 32 + wv * 8 + ns;
  if (gid >= count) return;
  int node = order[gid];
  int s = off[node], e = off[node + 1];
  const uint32_t* slab = (const uint32_t*)hlin_s + (size_t)slice * (SLAB16R / 2);
  float a0 = 0.f, a1 = 0.f;
  for (int j = s; j < e; j += 8) {
    int4 p0 = *(const int4*)(srcs + j);
    int4 p1 = *(const int4*)(srcs + j + 4);
    uint32_t u0 = slab[(size_t)p0.x * 8 + cd];
    uint32_t u1 = slab[(size_t)p0.y * 8 + cd];
    uint32_t u2 = slab[(size_t)p0.z * 8 + cd];
    uint32_t u3 = slab[(size_t)p0.w * 8 + cd];
    uint32_t u4 = slab[(size_t)p1.x * 8 + cd];
    uint32_t u5 = slab[(size_t)p1.y * 8 + cd];
    uint32_t u6 = slab[(size_t)p1.z * 8 + cd];
    uint32_t u7 = slab[(size_t)p1.w * 8 + cd];
    a0 += __uint_as_float(u0 << 16) + __uint_as_float(u1 << 16) +
          __uint_as_float(u2 << 16) + __uint_as_float(u3 << 16) +
          __uint_as_float(u4 << 16) + __uint_as_float(u5 << 16) +
          __uint_as_float(u6 << 16) + __uint_as_float(u7 << 16);
    a1 += __uint_as_float(u0 & 0xFFFF0000u) + __uint_as_float(u1 & 0xFFFF0000u) +
          __uint_as_float(u2 & 0xFFFF0000u) + __uint_as_float(u3 & 0xFFFF0000u) +
          __uint_as_float(u4 & 0xFFFF0000u) + __uint_as_float(u5 & 0xFFFF0000u) +
          __uint_as_float(u6 & 0xFFFF0000u) + __uint_as_float(u7 & 0xFFFF0000u);
  }
  float2 bv = ((const float2*)bias)[slice * 8 + cd];
  uint32_t* hb = (uint32_t*)hbf_s + (size_t)slice * (SLAB16R / 2);
  size_t hi = (size_t)node * 8 + cd;
  float h0, h1;
  if (first) {
    h0 = a0 + bv.x; h1 = a1 + bv.y;
  } else {
    uint32_t up = hb[hi];
    h0 = __uint_as_float(up << 16) + a0 + bv.x;
    h1 = __uint_as_float(up & 0xFFFF0000u) + a1 + bv.y;
  }
  if (last) {
    *(float2*)(outf + (size_t)node * 128 + slice * 16 + cd * 2) = make_float2(h0, h1);
  } else {
    hb[hi] = (uint32_t)f2b(h0) | ((uint32_t)f2b(h1) << 16);
  }
}

extern "C" void kernel_launch(void* const* d_in, const int* in_sizes, int n_in,
                              void* d_out, int out_size, void* d_ws, size_t ws_size,
                              hipStream_t stream) {
  const float* x = (const float*)d_in[0];
  const int* ei  = (const int*)d_in[1];
  const int* src = ei;
  const int* dst = ei + N_EDGES;
  const float* Wp[4] = {(const float*)d_in[4], (const float*)d_in[6],
                        (const float*)d_in[8], (const float*)d_in[10]};
  const float* bp[4] = {(const float*)d_in[5], (const float*)d_in[7],
                        (const float*)d_in[9], (const float*)d_in[11]};

  char* w = (char*)d_ws;
  auto alloc = [&](size_t bytes) {
    char* p = w;
    w += (bytes + 255) & ~(size_t)255;
    return p;
  };
  ushort* xs       = (ushort*)alloc(8 * SLAB16R * 2);
  ushort* hbf_s    = (ushort*)alloc(8 * SLAB16R * 2);
  ushort* hlin_s   = (ushort*)alloc(8 * SLAB16R * 2);
  int*    off      = (int*)   alloc((size_t)(N_NODES + 1) * 4);
  int*    srcs     = (int*)   alloc((size_t)SRCS_CAP * 4);
  int*    binned   = (int*)   alloc((size_t)NBUCK * BUCK_CAP * 4);
  int*    degg     = (int*)   alloc((size_t)N_NODES * 4);
  int*    order    = (int*)   alloc((size_t)N_NODES * 4);
  int*    rorder   = (int*)   alloc((size_t)N_ROOTS * 4);
  int*    bucket_cnt  = (int*)alloc((size_t)NBUCK * 4);
  int*    pad_cnt     = (int*)alloc((size_t)NBUCK * 4);
  int*    bucket_base = (int*)alloc((size_t)(NBUCK + 1) * 4);
  int*    dbinP    = (int*)   alloc(64 * 32 * 4);
  int*    rbinP    = (int*)   alloc(64 * 32 * 4);
  int*    dcurP    = (int*)   alloc(64 * 32 * 4);
  int*    rcurP    = (int*)   alloc(64 * 32 * 4);
  if ((size_t)(w - (char*)d_ws) > ws_size) return;

  hipMemsetAsync(bucket_cnt, 0, (size_t)NBUCK * 4, stream);
  hipMemsetAsync(dbinP, 0, 64 * 32 * 4, stream);
  hipMemsetAsync(rbinP, 0, 64 * 32 * 4, stream);
  for (int sl = 0; sl < 8; ++sl)
    hipMemsetAsync(hlin_s + (size_t)sl * SLAB16R + (size_t)N_NODES * 16, 0, 32, stream);

  k_cvt_sliced<<<2048, 256, 0, stream>>>(x, xs, N_NODES);
  k_bin<<<NB_BIN, 256, 0, stream>>>(src, dst, bucket_cnt, binned);
  k_deg<<<NBUCK, 512, 0, stream>>>(binned, bucket_cnt, degg, pad_cnt);
  k_bucket_scan<<<1, 256, 0, stream>>>(pad_cnt, bucket_base, off + N_NODES);
  k_csr<<<NBUCK, 512, 0, stream>>>(binned, bucket_cnt, bucket_base, degg, off, srcs);
  k_dhist<<<NB_DS, 256, 0, stream>>>(degg, dbinP, rbinP);
  k_dscan<<<1, 64, 0, stream>>>(dbinP, rbinP, dcurP, rcurP);
  k_dscat<<<NB_DS, 256, 0, stream>>>(degg, dcurP, rcurP, order, rorder);

  int gblocks = (N_NODES + 255) / 256;
  int afull = ((N_NODES + 31) / 32) * 8;
  int aroot = ((N_ROOTS + 31) / 32) * 8;
  // layer 0
  k_gemm<<<gblocks, 512, 128 * 128 * 2, stream>>>(xs, xs, Wp[0], hlin_s, N_NODES, 128, 0);
  k_aggr<<<afull, 256, 0, stream>>>(hlin_s, off, srcs, order, bp[0], hbf_s, (float*)d_out,
                                    N_NODES, 1, 0);
  // layers 1..2 full, layer 3 aggregation root-only
  for (int l = 1; l < 4; ++l) {
    k_gemm<<<gblocks, 512, 256 * 128 * 2, stream>>>(hbf_s, xs, Wp[l], hlin_s, N_NODES, 256, 1);
    if (l < 3) {
      k_aggr<<<afull, 256, 0, stream>>>(hlin_s, off, srcs, order, bp[l], hbf_s, (float*)d_out,
                                        N_NODES, 0, 0);
    } else {
      k_aggr<<<aroot, 256, 0, stream>>>(hlin_s, off, srcs, rorder, bp[l], hbf_s, (float*)d_out,
                                        N_ROOTS, 0, 1);
    }
  }
}

// Round 11
// 345.415 us; speedup vs baseline: 3.4186x; 1.2485x over previous
//
#include <hip/hip_runtime.h>
#include <hip/hip_bf16.h>
#include <stdint.h>

#define N_NODES 100000
#define N_EDGES 1600000
#define FEAT 128
#define EMB 128
#define N_ROOTS 4096

#define BUCKET_BITS 9
#define BUCKET_NODES 512
#define NBUCK ((N_NODES + BUCKET_NODES - 1) / BUCKET_NODES)  // 196
#define BUCK_CAP 12288
#define BIN_CHUNK 4096
#define NB_BIN ((N_EDGES + BIN_CHUNK - 1) / BIN_CHUNK)       // 391
#define BUCK_SLACK 4096                                      // >= 512*7 pad slack per bucket
#define SRCS_CAP (N_EDGES + NBUCK * BUCK_SLACK + 4096)

typedef __attribute__((ext_vector_type(4))) float f32x4;
typedef __attribute__((ext_vector_type(8))) short bf16x8;

__device__ __forceinline__ ushort f2b(float f) {
  uint32_t u = __float_as_uint(f);
  uint32_t r = (u + 0x7FFFu + ((u >> 16) & 1u)) >> 16;  // RNE
  return (ushort)r;
}

__global__ void k_cvt_bf16(const float* __restrict__ in, ushort* __restrict__ out, int n4) {
  int i = blockIdx.x * blockDim.x + threadIdx.x;
  int stride = gridDim.x * blockDim.x;
  for (; i < n4; i += stride) {
    float4 v = ((const float4*)in)[i];
    ushort4 o;
    o.x = f2b(v.x); o.y = f2b(v.y); o.z = f2b(v.z); o.w = f2b(v.w);
    ((ushort4*)out)[i] = o;
  }
}

// W (f32 [K][128]) -> bf16, pre-swizzled to the GEMM LDS layout:
// byte addr = c*2K + ((2k) ^ ((c&7)<<4))
__global__ void k_cvtW(const float* __restrict__ W, ushort* __restrict__ Wswz, int K) {
  int idx = blockIdx.x * blockDim.x + threadIdx.x;
  if (idx >= K * 128) return;
  int k = idx >> 7, c = idx & 127;
  ushort b = f2b(W[idx]);
  *(ushort*)((char*)Wswz + c * (K * 2) + ((k * 2) ^ ((c & 7) << 4))) = b;
}

// ---- bucketed CSR build ----
__global__ __launch_bounds__(256) void k_bin(const int* __restrict__ srcA, const int* __restrict__ dstA,
                                             int* __restrict__ bucket_cnt, int* __restrict__ binned) {
  __shared__ int hist[NBUCK];
  __shared__ int lscan[NBUCK];
  __shared__ int rsv[NBUCK];
  __shared__ int lpos[NBUCK];
  __shared__ int ws[4];
  __shared__ int2 ent[BIN_CHUNK];
  int t = threadIdx.x;
  int e0 = blockIdx.x * BIN_CHUNK;
  int cnt = min(BIN_CHUNK, N_EDGES - e0);
  for (int i = t; i < NBUCK; i += 256) hist[i] = 0;
  __syncthreads();
  for (int j = t; j < cnt; j += 256) atomicAdd(&hist[dstA[e0 + j] >> BUCKET_BITS], 1);
  __syncthreads();
  {
    int lane = t & 63, wv = t >> 6;
    int v = (t < NBUCK) ? hist[t] : 0;
    int inc = v;
    for (int d = 1; d < 64; d <<= 1) { int x = __shfl_up(inc, d); if (lane >= d) inc += x; }
    if (lane == 63) ws[wv] = inc;
    __syncthreads();
    int wbase = 0;
    for (int k = 0; k < wv; ++k) wbase += ws[k];
    if (t < NBUCK) {
      int excl = wbase + inc - v;
      lscan[t] = excl;
      lpos[t] = excl;
      rsv[t] = (v > 0) ? atomicAdd(&bucket_cnt[t], v) : 0;
    }
  }
  __syncthreads();
  for (int j = t; j < cnt; j += 256) {
    int s = srcA[e0 + j], d = dstA[e0 + j];
    int p = atomicAdd(&lpos[d >> BUCKET_BITS], 1);
    ent[p] = make_int2(s, d);
  }
  __syncthreads();
  for (int j = t; j < cnt; j += 256) {
    int2 E = ent[j];
    int b = E.y >> BUCKET_BITS;
    int pos = rsv[b] + (j - lscan[b]);
    if (pos < BUCK_CAP)
      binned[b * BUCK_CAP + pos] = (E.x << BUCKET_BITS) | (E.y & (BUCKET_NODES - 1));
  }
}

// scan UNPADDED bucket counts; per-bucket base gets +b*BUCK_SLACK headroom for padding
__global__ __launch_bounds__(256) void k_bucket_scan(const int* __restrict__ bucket_cnt,
                                                     int* __restrict__ bucket_base) {
  __shared__ int ws[4];
  int t = threadIdx.x;
  int lane = t & 63, wv = t >> 6;
  int v = (t < NBUCK) ? bucket_cnt[t] : 0;
  int inc = v;
  for (int d = 1; d < 64; d <<= 1) { int x = __shfl_up(inc, d); if (lane >= d) inc += x; }
  if (lane == 63) ws[wv] = inc;
  __syncthreads();
  int wbase = 0;
  for (int k = 0; k < wv; ++k) wbase += ws[k];
  if (t < NBUCK) bucket_base[t] = (wbase + inc - v) + t * BUCK_SLACK;
}

// per-bucket: LDS degrees + padded scan + scatter + dummy fill; writes off2 = {start,end}
__global__ __launch_bounds__(512) void k_csr(const int* __restrict__ binned,
                                             const int* __restrict__ bucket_cnt,
                                             const int* __restrict__ bucket_base,
                                             int2* __restrict__ off2, int* __restrict__ srcs) {
  __shared__ int deg[BUCKET_NODES];
  __shared__ int sAb[BUCKET_NODES];
  __shared__ int sBb[BUCKET_NODES];
  __shared__ int pos[BUCKET_NODES];
  __shared__ int epk[BUCK_CAP];
  int b = blockIdx.x;
  int t = threadIdx.x;
  int cnt = min(bucket_cnt[b], BUCK_CAP);
  int gbase = bucket_base[b];
  int n0 = b * BUCKET_NODES;
  int nn = min(BUCKET_NODES, N_NODES - n0);
  deg[t] = 0;
  __syncthreads();
  for (int j = t; j < cnt; j += 512) {
    int p = binned[b * BUCK_CAP + j];
    epk[j] = p;
    atomicAdd(&deg[p & (BUCKET_NODES - 1)], 1);
  }
  __syncthreads();
  int d = deg[t];
  int dp = (d + 7) & ~7;
  int* sA = sAb; int* sB = sBb;
  sA[t] = dp;
  __syncthreads();
  for (int q = 1; q < 512; q <<= 1) {
    int x = sA[t];
    if (t >= q) x += sA[t - q];
    sB[t] = x;
    __syncthreads();
    int* tp = sA; sA = sB; sB = tp;
  }
  int ex = sA[t] - dp;   // exclusive padded scan
  pos[t] = ex;
  if (t < nn) off2[n0 + t] = make_int2(gbase + ex, gbase + ex + dp);
  __syncthreads();
  for (int j = t; j < cnt; j += 512) {
    int p = epk[j];
    int q = atomicAdd(&pos[p & (BUCKET_NODES - 1)], 1);
    srcs[gbase + q] = p >> BUCKET_BITS;
  }
  __syncthreads();
  for (int q = ex + d; q < ex + dp; ++q) srcs[gbase + q] = N_NODES;  // zero-row dummies
}

// out[n][128](bf16) = A @ W; A = A0|A1 split at k=128 (optional relu on A0);
// W pre-swizzled bf16; A-loads prefetched one k-step ahead.
__global__ __launch_bounds__(256) void k_gemm(
    const ushort* __restrict__ A0, const ushort* __restrict__ A1,
    const ushort* __restrict__ Wswz, ushort* __restrict__ out, int n, int K, int relu0)
{
  extern __shared__ char smem[];
  int bytes = K * 256;  // K*128*2
  for (int idx = threadIdx.x * 16; idx < bytes; idx += 256 * 16)
    *(uint4*)(smem + idx) = *(const uint4*)((const char*)Wswz + idx);
  __syncthreads();

  int lane = threadIdx.x & 63;
  int wv = threadIdx.x >> 6;
  int rowBase = blockIdx.x * 128 + wv * 32;
  int rl = lane & 15;
  int kh = lane >> 4;
  int r0 = rowBase + rl, r1 = r0 + 16;
  int r0c = min(r0, n - 1), r1c = min(r1, n - 1);

  f32x4 acc[2][8];
#pragma unroll
  for (int i = 0; i < 2; ++i)
#pragma unroll
    for (int j = 0; j < 8; ++j)
      acc[i][j] = (f32x4){0.f, 0.f, 0.f, 0.f};

  int nks = K >> 5;
  bf16x8 a0, a1;
  {
    const ushort* Asrc = A0;
    int kof = (kh << 3);
    a0 = *(const bf16x8*)(Asrc + (size_t)r0c * 128 + kof);
    a1 = *(const bf16x8*)(Asrc + (size_t)r1c * 128 + kof);
  }
  for (int ks = 0; ks < nks; ++ks) {
    bf16x8 na0 = a0, na1 = a1;
    if (ks + 1 < nks) {
      int ksn = ks + 1;
      const ushort* Asrc = (ksn < 4) ? A0 : A1;
      int kof = ((ksn & 3) << 5) + (kh << 3);
      na0 = *(const bf16x8*)(Asrc + (size_t)r0c * 128 + kof);
      na1 = *(const bf16x8*)(Asrc + (size_t)r1c * 128 + kof);
    }
    if (relu0 && ks < 4) {
#pragma unroll
      for (int q = 0; q < 8; ++q) {
        short v0 = a0[q]; a0[q] = (short)(v0 & ~(v0 >> 15));
        short v1 = a1[q]; a1[q] = (short)(v1 & ~(v1 >> 15));
      }
    }
    int kk = (ks << 5) + (kh << 3);
#pragma unroll
    for (int ct = 0; ct < 8; ++ct) {
      int col = (ct << 4) + rl;
      bf16x8 b = *(const bf16x8*)(smem + col * (K * 2) + ((kk * 2) ^ ((col & 7) << 4)));
      acc[0][ct] = __builtin_amdgcn_mfma_f32_16x16x32_bf16(a0, b, acc[0][ct], 0, 0, 0);
      acc[1][ct] = __builtin_amdgcn_mfma_f32_16x16x32_bf16(a1, b, acc[1][ct], 0, 0, 0);
    }
    a0 = na0; a1 = na1;
  }
#pragma unroll
  for (int ri = 0; ri < 2; ++ri)
#pragma unroll
    for (int ct = 0; ct < 8; ++ct) {
      int col = (ct << 4) + rl;
#pragma unroll
      for (int j = 0; j < 4; ++j) {
        int row = rowBase + ri * 16 + kh * 4 + j;
        if (row < n) out[(size_t)row * 128 + col] = f2b(acc[ri][ct][j]);
      }
    }
}

// segment sum, padded CSR: 1 wave/node, 2 cols/lane, unroll-16 two-phase
__global__ __launch_bounds__(256) void k_aggr(
    const ushort* __restrict__ hlin, const int2* __restrict__ off2, const int* __restrict__ srcs,
    const float* __restrict__ bias, ushort* __restrict__ hbf, float* __restrict__ outf,
    int n, int first, int last)
{
  int node = blockIdx.x * 4 + (threadIdx.x >> 6);
  if (node >= n) return;
  int lane = threadIdx.x & 63;
  int2 se = off2[node];
  int s = __builtin_amdgcn_readfirstlane(se.x);
  int e = __builtin_amdgcn_readfirstlane(se.y);
  float a0 = 0.f, a1 = 0.f;
  int j = s;
  for (; j + 16 <= e; j += 16) {
    int ix[16];
#pragma unroll
    for (int q = 0; q < 16; ++q) ix[q] = srcs[j + q];
    uint32_t u[16];
#pragma unroll
    for (int q = 0; q < 16; ++q)
      u[q] = *(const uint32_t*)(hlin + (size_t)ix[q] * 128 + lane * 2);
#pragma unroll
    for (int q = 0; q < 16; ++q) {
      a0 += __uint_as_float(u[q] << 16);
      a1 += __uint_as_float(u[q] & 0xFFFF0000u);
    }
  }
  if (j < e) {  // remainder exactly 8 (degrees padded to x8)
    int ix[8];
#pragma unroll
    for (int q = 0; q < 8; ++q) ix[q] = srcs[j + q];
    uint32_t u[8];
#pragma unroll
    for (int q = 0; q < 8; ++q)
      u[q] = *(const uint32_t*)(hlin + (size_t)ix[q] * 128 + lane * 2);
#pragma unroll
    for (int q = 0; q < 8; ++q) {
      a0 += __uint_as_float(u[q] << 16);
      a1 += __uint_as_float(u[q] & 0xFFFF0000u);
    }
  }
  float2 bv = ((const float2*)bias)[lane];
  size_t idx = (size_t)node * 128 + lane * 2;
  float h0, h1;
  if (first) {
    h0 = a0 + bv.x; h1 = a1 + bv.y;
  } else {
    uint32_t up = *(const uint32_t*)(hbf + idx);
    h0 = __uint_as_float(up << 16) + a0 + bv.x;
    h1 = __uint_as_float(up & 0xFFFF0000u) + a1 + bv.y;
  }
  if (last) {
    *(float2*)(outf + idx) = make_float2(h0, h1);
  } else {
    ushort2 r; r.x = f2b(h0); r.y = f2b(h1);
    *(ushort2*)(hbf + idx) = r;
  }
}

extern "C" void kernel_launch(void* const* d_in, const int* in_sizes, int n_in,
                              void* d_out, int out_size, void* d_ws, size_t ws_size,
                              hipStream_t stream) {
  const float* x = (const float*)d_in[0];
  const int* ei  = (const int*)d_in[1];
  const int* src = ei;
  const int* dst = ei + N_EDGES;
  const float* Wp[4] = {(const float*)d_in[4], (const float*)d_in[6],
                        (const float*)d_in[8], (const float*)d_in[10]};
  const float* bp[4] = {(const float*)d_in[5], (const float*)d_in[7],
                        (const float*)d_in[9], (const float*)d_in[11]};
  const int Kl[4] = {128, 256, 256, 256};

  char* w = (char*)d_ws;
  auto alloc = [&](size_t bytes) {
    char* p = w;
    w += (bytes + 255) & ~(size_t)255;
    return p;
  };
  ushort* x_bf     = (ushort*)alloc((size_t)N_NODES * 128 * 2);
  ushort* hbf      = (ushort*)alloc((size_t)N_NODES * 128 * 2);
  ushort* hlin     = (ushort*)alloc((size_t)(N_NODES + 8) * 128 * 2);  // +zero row
  int2*   off2     = (int2*)  alloc((size_t)N_NODES * 8);
  int*    srcs     = (int*)   alloc((size_t)SRCS_CAP * 4);
  int*    binned   = (int*)   alloc((size_t)NBUCK * BUCK_CAP * 4);
  int*    bucket_cnt  = (int*)alloc((size_t)NBUCK * 4);
  int*    bucket_base = (int*)alloc((size_t)NBUCK * 4);
  ushort* Wswz[4];
  for (int l = 0; l < 4; ++l) Wswz[l] = (ushort*)alloc((size_t)Kl[l] * 128 * 2);
  if ((size_t)(w - (char*)d_ws) > ws_size) return;

  hipMemsetAsync(bucket_cnt, 0, (size_t)NBUCK * 4, stream);
  hipMemsetAsync(hlin + (size_t)N_NODES * 128, 0, 256, stream);  // zero row for dummies
  k_cvt_bf16<<<2048, 256, 0, stream>>>(x, x_bf, N_NODES * 128 / 4);
  for (int l = 0; l < 4; ++l)
    k_cvtW<<<(Kl[l] * 128 + 255) / 256, 256, 0, stream>>>(Wp[l], Wswz[l], Kl[l]);
  k_bin<<<NB_BIN, 256, 0, stream>>>(src, dst, bucket_cnt, binned);
  k_bucket_scan<<<1, 256, 0, stream>>>(bucket_cnt, bucket_base);
  k_csr<<<NBUCK, 512, 0, stream>>>(binned, bucket_cnt, bucket_base, off2, srcs);

  int gblocks = (N_NODES + 127) / 128;
  int ablocks = (N_NODES + 3) / 4;
  // layer 0
  k_gemm<<<gblocks, 256, 128 * 128 * 2, stream>>>(x_bf, x_bf, Wswz[0], hlin, N_NODES, 128, 0);
  k_aggr<<<ablocks, 256, 0, stream>>>(hlin, off2, srcs, bp[0], hbf, (float*)d_out, N_NODES, 1, 0);
  // layers 1..2 full, layer 3 aggregation root-only (roots = nodes 0..4095)
  for (int l = 1; l < 4; ++l) {
    k_gemm<<<gblocks, 256, 256 * 128 * 2, stream>>>(hbf, x_bf, Wswz[l], hlin, N_NODES, 256, 1);
    if (l < 3) {
      k_aggr<<<ablocks, 256, 0, stream>>>(hlin, off2, srcs, bp[l], hbf, (float*)d_out,
                                          N_NODES, 0, 0);
    } else {
      k_aggr<<<(N_ROOTS + 3) / 4, 256, 0, stream>>>(hlin, off2, srcs, bp[l], hbf, (float*)d_out,
                                                    N_ROOTS, 0, 1);
    }
  }
}